// Round 1
// baseline (472.201 us; speedup 1.0000x reference)
//
#include <hip/hip_runtime.h>

// LateralInhibition: out = inputs * ((inputs @ w1 + b) > 0), w1 = w with zero diag.
// inputs: [M=32768, 512] fp32 row-major; w: [512,512] fp32 row-major (w[k][n]).
// fp32 vector-ALU SGEMM (no fp32 MFMA on CDNA4), BM=BN=128 BK=32, 8x8/thread.
//
// v2: W streamed from L1/L2 via 2-slot register pipeline (was LDS-staged).
//     Rationale: at 8x8/thread with both operands in LDS, LDS read BW (128 B/cyc/CU)
//     exactly co-limits with the FMA pipe, and the Bs reads were 4-way bank-conflicted
//     (SQ_LDS_BANK_CONFLICT ~2.25 cyc/read). A-side LDS reads are 16-way broadcasts
//     (conflict-free); W is 1 MB = L2-resident and shared by all blocks on a CU
//     (same n0 slab), so it streams from cache at register cost.
//     Diagonal zeroing hoisted to a 1 MB preprocess kernel into d_ws.

#define NUMD 512
#define BM 128
#define BN 128
#define BK 32
#define TM 8
#define TN 8
#define PAD 4            // LDS row pad: staging writes 2-way (free), reads broadcast
#define NKT (NUMD / BK)  // 16

__global__ __launch_bounds__(256) void zero_diag_kernel(
    const float* __restrict__ W, float* __restrict__ Wz)
{
    const int f = (int)(blockIdx.x * blockDim.x + threadIdx.x) * 4; // flat float idx
    const int row  = f >> 9;
    const int col0 = f & 511;
    float4 v = *(const float4*)(W + f);
    if (row == col0 + 0) v.x = 0.0f;
    if (row == col0 + 1) v.y = 0.0f;
    if (row == col0 + 2) v.z = 0.0f;
    if (row == col0 + 3) v.w = 0.0f;
    *(float4*)(Wz + f) = v;
}

template<bool SUBDIAG>
__global__ __launch_bounds__(256, 4) void li_gemm_gate(
    const float* __restrict__ A,    // [M, 512]
    const float* __restrict__ Wm,   // zero-diag W (SUBDIAG=0) or raw W (SUBDIAG=1)
    const float* __restrict__ bias, // [512]
    float* __restrict__ out,        // [M, 512]
    int M)
{
    __shared__ __align__(16) float As[BK][BM + PAD]; // transposed: As[k][m]

    const int tid = threadIdx.x;
    const int tc  = tid & 15;   // column group (n), fast -> coalesced C writes
    const int tr  = tid >> 4;   // row group (m)
    const int m0  = blockIdx.x * BM;
    const int n0  = blockIdx.y * BN;

    // A staging: thread loads 16 consecutive k-floats of one row (4x float4)
    const int arow = tid >> 1;          // 0..127
    const int acol = (tid & 1) * 16;    // 0 or 16

    const float* Aptr = A + (size_t)(m0 + arow) * NUMD + acol;
    const float* Wp   = Wm + n0 + tc * TN;   // + k*NUMD per k-step

    float acc[TM][TN];
#pragma unroll
    for (int i = 0; i < TM; ++i)
#pragma unroll
        for (int j = 0; j < TN; ++j) acc[i][j] = 0.0f;

    // A-tile register prefetch (tile 0)
    float4 ast0 = *(const float4*)(Aptr + 0);
    float4 ast1 = *(const float4*)(Aptr + 4);
    float4 ast2 = *(const float4*)(Aptr + 8);
    float4 ast3 = *(const float4*)(Aptr + 12);

    // W register pipeline: 2 slots, distance-1 prefetch
    float4 w0a = *(const float4*)(Wp + 0);   // k = 0
    float4 w0b = *(const float4*)(Wp + 4);
    float4 w1a, w1b;

    for (int kt = 0; kt < NKT; ++kt) {
        // stage A regs -> LDS (transposed). 16 scalar stores, 2-way banked (free).
#pragma unroll
        for (int e = 0; e < 4; ++e) {
            As[acol + 0  + e][arow] = ((const float*)&ast0)[e];
            As[acol + 4  + e][arow] = ((const float*)&ast1)[e];
            As[acol + 8  + e][arow] = ((const float*)&ast2)[e];
            As[acol + 12 + e][arow] = ((const float*)&ast3)[e];
        }
        __syncthreads();

        // prefetch next A tile while computing this one
        if (kt + 1 < NKT) {
            Aptr += BK;
            ast0 = *(const float4*)(Aptr + 0);
            ast1 = *(const float4*)(Aptr + 4);
            ast2 = *(const float4*)(Aptr + 8);
            ast3 = *(const float4*)(Aptr + 12);
        }

        const int kbase = kt * BK;
#pragma unroll 2
        for (int k2 = 0; k2 < BK; k2 += 2) {
            // ---- even step: compute k = kbase+k2 with slot0, load k+1 into slot1
            {
                const int kn = kbase + k2 + 1;   // <= 511 always
                w1a = *(const float4*)(Wp + (size_t)kn * NUMD);
                w1b = *(const float4*)(Wp + (size_t)kn * NUMD + 4);
            }
            {
                const float* ap = &As[k2][tr * TM];
                float4 a0 = *(const float4*)ap;
                float4 a1 = *(const float4*)(ap + 4);
                float a[TM] = {a0.x, a0.y, a0.z, a0.w, a1.x, a1.y, a1.z, a1.w};
                float b[TN] = {w0a.x, w0a.y, w0a.z, w0a.w, w0b.x, w0b.y, w0b.z, w0b.w};
#pragma unroll
                for (int i = 0; i < TM; ++i)
#pragma unroll
                    for (int j = 0; j < TN; ++j)
                        acc[i][j] = fmaf(a[i], b[j], acc[i][j]);
            }
            // ---- odd step: compute k = kbase+k2+1 with slot1, load k+2 into slot0
            {
                int kn = kbase + k2 + 2;
                if (kn > 511) kn = 511;          // harmless duplicate at the very end
                w0a = *(const float4*)(Wp + (size_t)kn * NUMD);
                w0b = *(const float4*)(Wp + (size_t)kn * NUMD + 4);
            }
            {
                const float* ap = &As[k2 + 1][tr * TM];
                float4 a0 = *(const float4*)ap;
                float4 a1 = *(const float4*)(ap + 4);
                float a[TM] = {a0.x, a0.y, a0.z, a0.w, a1.x, a1.y, a1.z, a1.w};
                float b[TN] = {w1a.x, w1a.y, w1a.z, w1a.w, w1b.x, w1b.y, w1b.z, w1b.w};
#pragma unroll
                for (int i = 0; i < TM; ++i)
#pragma unroll
                    for (int j = 0; j < TN; ++j)
                        acc[i][j] = fmaf(a[i], b[j], acc[i][j]);
            }
        }
        __syncthreads();
    }

    // epilogue: out[m][n] = in[m][n] * ((acc + b[n] [- in*Wdiag]) > 0)
    float bv[TN];
#pragma unroll
    for (int j = 0; j < TN; ++j) bv[j] = bias[n0 + tc * TN + j];

    float wd[TN];
    if (SUBDIAG) {
#pragma unroll
        for (int j = 0; j < TN; ++j) {
            const int n = n0 + tc * TN + j;
            wd[j] = Wm[(size_t)n * NUMD + n];
        }
    }

#pragma unroll
    for (int i = 0; i < TM; ++i) {
        const int gm = m0 + tr * TM + i;
        const float* inrow = A + (size_t)gm * NUMD + n0 + tc * TN;
        float4 x0 = *(const float4*)inrow;
        float4 x1 = *(const float4*)(inrow + 4);
        float x[TN] = {x0.x, x0.y, x0.z, x0.w, x1.x, x1.y, x1.z, x1.w};
        float o[TN];
#pragma unroll
        for (int j = 0; j < TN; ++j) {
            float inh = acc[i][j] + bv[j];
            if (SUBDIAG) inh = fmaf(-x[j], wd[j], inh);
            o[j] = (inh > 0.0f) ? x[j] : 0.0f;
        }
        float4 o0 = {o[0], o[1], o[2], o[3]};
        float4 o1 = {o[4], o[5], o[6], o[7]};
        float* orow = out + (size_t)gm * NUMD + n0 + tc * TN;
        *(float4*)orow       = o0;
        *(float4*)(orow + 4) = o1;
    }
}

extern "C" void kernel_launch(void* const* d_in, const int* in_sizes, int n_in,
                              void* d_out, int out_size, void* d_ws, size_t ws_size,
                              hipStream_t stream) {
    const float* A    = (const float*)d_in[0]; // inputs [8*4096, 512]
    const float* W    = (const float*)d_in[1]; // w [512, 512]
    const float* bias = (const float*)d_in[2]; // b [512]
    float* out        = (float*)d_out;

    const int M = in_sizes[0] / NUMD; // 32768
    dim3 grid(M / BM, NUMD / BN);     // (256, 4)

    const size_t wbytes = (size_t)NUMD * NUMD * sizeof(float);
    if (ws_size >= wbytes) {
        float* Wz = (float*)d_ws;
        // 512*512/4 float4s / 256 threads = 256 blocks
        zero_diag_kernel<<<dim3(NUMD * NUMD / (4 * 256)), 256, 0, stream>>>(W, Wz);
        li_gemm_gate<false><<<grid, 256, 0, stream>>>(A, Wz, bias, out, M);
    } else {
        li_gemm_gate<true><<<grid, 256, 0, stream>>>(A, W, bias, out, M);
    }
}

// Round 3
// 321.223 us; speedup vs baseline: 1.4700x; 1.4700x over previous
//
#include <hip/hip_runtime.h>

// LateralInhibition: out = inputs * ((inputs @ w1 + b) > 0), w1 = w with zero diag.
// inputs: [M=32768, 512] fp32 row-major; w: [512,512] fp32 row-major (w[k][n]).
// fp32 vector-ALU SGEMM (no fp32 MFMA on CDNA4).
//
// v3 (resubmit after infra failure): BM=128, BN=256, BK=16, thread tile 8x16.
//     Rationale (measured): v1 (8x8, both operands LDS) was LDS-issue-bound:
//     4 ds_read_b128/wave/k x 12cyc x 4 waves = 192 cyc vs 128 VALU cyc -> 54%,
//     matching VALUBusy=58%. v2 (W from L2) was latency-bound (47%, 412us).
//     8x16 tile: 6 ds_read_b128/wave/k feed 128 FMAs -> LDS 288 vs VALU 256 cyc.
//     B-frag read as 4 chunks at stride 64 floats: bank-quads tc%8 -> 2-way (free).
//     A-frag is a 16-lane broadcast (conflict-free).

#define NUMD 512
#define BM 128
#define BN 256
#define BK 16
#define TM 8
#define TN 16
#define PAD 4
#define NT (NUMD / BK)   // 32

__global__ __launch_bounds__(256, 2) void li_gemm_gate(
    const float* __restrict__ A,    // [M, 512]
    const float* __restrict__ W,    // [512, 512]
    const float* __restrict__ bias, // [512]
    float* __restrict__ out,        // [M, 512]
    int M)
{
    __shared__ __align__(16) float As[BK][BM + PAD]; // transposed: As[k][m]
    __shared__ __align__(16) float Bs[BK][BN + PAD]; // Bs[k][n]

    const int tid = threadIdx.x;
    const int tc  = tid & 15;   // column group (n)
    const int tr  = tid >> 4;   // row group (m)
    const int m0  = blockIdx.x * BM;
    const int n0  = blockIdx.y * BN;

    // --- staging index maps ---
    // A: 128x16 tile, thread loads 8 consecutive k-floats of one row
    const int arow = tid >> 1;         // 0..127
    const int acol = (tid & 1) * 8;    // 0 or 8
    // B: 16x256 tile, thread loads 4 float4s of row brow at cols 4*tc + 64*e
    const int brow = tr;               // 0..15
    const int bcol = tc * 4;           // 0..60

    const float* Aptr = A + (size_t)(m0 + arow) * NUMD + acol;
    const float* Wptr = W + (size_t)brow * NUMD + n0 + bcol;

    float acc[TM][TN];
#pragma unroll
    for (int i = 0; i < TM; ++i)
#pragma unroll
        for (int j = 0; j < TN; ++j) acc[i][j] = 0.0f;

    // prefetch tile 0 into registers
    float4 ar0 = *(const float4*)(Aptr);
    float4 ar1 = *(const float4*)(Aptr + 4);
    float4 br[4];
#pragma unroll
    for (int e = 0; e < 4; ++e) br[e] = *(const float4*)(Wptr + 64 * e);

    for (int kt = 0; kt < NT; ++kt) {
        const int kk = kt * BK;

        // zero the diagonal of W during staging: element (kk+brow, n0+4tc+64e+d)
#pragma unroll
        for (int e = 0; e < 4; ++e) {
            int d = (kk + brow) - (n0 + bcol + 64 * e);
            if (d >= 0 && d < 4) ((float*)&br[e])[d] = 0.0f;
        }

        // store staged regs to LDS (A transposed; scalar stores are 2-way banked = free)
#pragma unroll
        for (int j = 0; j < 4; ++j) {
            As[acol + j][arow]     = ((const float*)&ar0)[j];
            As[acol + 4 + j][arow] = ((const float*)&ar1)[j];
        }
#pragma unroll
        for (int e = 0; e < 4; ++e)
            *(float4*)&Bs[brow][bcol + 64 * e] = br[e];
        __syncthreads();

        // prefetch next tile while computing this one
        if (kt + 1 < NT) {
            Aptr += BK;
            Wptr += (size_t)BK * NUMD;
            ar0 = *(const float4*)(Aptr);
            ar1 = *(const float4*)(Aptr + 4);
#pragma unroll
            for (int e = 0; e < 4; ++e) br[e] = *(const float4*)(Wptr + 64 * e);
        }

        // inner product over this K-slab
#pragma unroll
        for (int k = 0; k < BK; ++k) {
            const float* ap = &As[k][tr * TM];
            float4 a0 = *(const float4*)ap;
            float4 a1 = *(const float4*)(ap + 4);
            float a[TM] = {a0.x, a0.y, a0.z, a0.w, a1.x, a1.y, a1.z, a1.w};
            float b[TN];
#pragma unroll
            for (int c = 0; c < 4; ++c) {
                float4 b4 = *(const float4*)&Bs[k][tc * 4 + 64 * c];
                b[4 * c + 0] = b4.x; b[4 * c + 1] = b4.y;
                b[4 * c + 2] = b4.z; b[4 * c + 3] = b4.w;
            }
#pragma unroll
            for (int i = 0; i < TM; ++i)
#pragma unroll
                for (int j = 0; j < TN; ++j)
                    acc[i][j] = fmaf(a[i], b[j], acc[i][j]);
        }
        __syncthreads();
    }

    // epilogue: out[m][n] = in[m][n] * ((acc + b[n]) > 0)
    // thread's columns: n0 + 4*tc + 64*c + j, c=0..3, j=0..3
    float bv[TN];
#pragma unroll
    for (int c = 0; c < 4; ++c) {
        float4 b4 = *(const float4*)(bias + n0 + tc * 4 + 64 * c);
        bv[4 * c + 0] = b4.x; bv[4 * c + 1] = b4.y;
        bv[4 * c + 2] = b4.z; bv[4 * c + 3] = b4.w;
    }

#pragma unroll
    for (int i = 0; i < TM; ++i) {
        const int gm = m0 + tr * TM + i;
        const float* inrow = A + (size_t)gm * NUMD + n0 + tc * 4;
        float* orow       = out + (size_t)gm * NUMD + n0 + tc * 4;
#pragma unroll
        for (int c = 0; c < 4; ++c) {
            float4 x = *(const float4*)(inrow + 64 * c);
            float4 o;
            o.x = (acc[i][4*c+0] + bv[4*c+0] > 0.0f) ? x.x : 0.0f;
            o.y = (acc[i][4*c+1] + bv[4*c+1] > 0.0f) ? x.y : 0.0f;
            o.z = (acc[i][4*c+2] + bv[4*c+2] > 0.0f) ? x.z : 0.0f;
            o.w = (acc[i][4*c+3] + bv[4*c+3] > 0.0f) ? x.w : 0.0f;
            *(float4*)(orow + 64 * c) = o;
        }
    }
}

extern "C" void kernel_launch(void* const* d_in, const int* in_sizes, int n_in,
                              void* d_out, int out_size, void* d_ws, size_t ws_size,
                              hipStream_t stream) {
    const float* A    = (const float*)d_in[0]; // inputs [8*4096, 512]
    const float* W    = (const float*)d_in[1]; // w [512, 512]
    const float* bias = (const float*)d_in[2]; // b [512]
    float* out        = (float*)d_out;

    const int M = in_sizes[0] / NUMD; // 32768
    dim3 grid(M / BM, NUMD / BN);     // (256, 2)
    li_gemm_gate<<<grid, 256, 0, stream>>>(A, W, bias, out, M);
}

// Round 4
// 283.200 us; speedup vs baseline: 1.6674x; 1.1343x over previous
//
#include <hip/hip_runtime.h>
#include <stdint.h>

// LateralInhibition: out = inputs * ((inputs @ w1 + b) > 0), w1 = w with zero diag.
// inputs: [M=32768, 512] fp32 row-major; w: [512,512] fp32 row-major (w[k][n]).
// fp32 vector-ALU SGEMM (no fp32 MFMA on CDNA4).
//
// v4: m97-structure pipeline. BM=128 BN=256 BK=16, 8x16/thread, 256 thr.
//  - global_load_lds width=16 for BOTH A and B (no staging registers, no
//    reg->LDS round trip). Loads for tile t+1 issued right after tile-t's
//    publish barrier; the NEXT __syncthreads' vmcnt(0) drain lands ~4000 cyc
//    later -> HBM latency fully hidden (minimum 2-phase schedule, T3 recipe).
//  - As stored [m][k] (linear, as global_load_lds requires); A-frag read as
//    b128 over 4 k's. 4-way bank conflict fixed by XOR swizzle q ^= (m>>3)&3
//    applied on BOTH the per-lane global source and the compute read (rule 21).
//  - Bs linear [16][256]: compute reads are 2-way + 4-lane broadcast = free.
//  - diag zeroing: preprocess W into d_ws (exact); fallback zeroes diag in LDS
//    between two barriers (exact).
//  - v3 post-mortem: VGPR_Count=128 (allocator clamp + spill) and per-tile
//    vmcnt drains -> VALUBusy 52%. launch_bounds(256,1) frees the allocator.

#define NUMD 512
#define BM 128
#define BN 256
#define BK 16
#define TM 8
#define TN 16
#define NT (NUMD / BK)   // 32

#define GLOAD_LDS16(g, l)                                                      \
  __builtin_amdgcn_global_load_lds(                                            \
      (const __attribute__((address_space(1))) void*)(g),                      \
      (__attribute__((address_space(3))) void*)(l), 16, 0, 0)

__global__ __launch_bounds__(256) void zero_diag_kernel(
    const float* __restrict__ W, float* __restrict__ Wz)
{
    const int f = (int)(blockIdx.x * blockDim.x + threadIdx.x) * 4;
    const int row  = f >> 9;
    const int col0 = f & 511;
    float4 v = *(const float4*)(W + f);
    if (row == col0 + 0) v.x = 0.0f;
    if (row == col0 + 1) v.y = 0.0f;
    if (row == col0 + 2) v.z = 0.0f;
    if (row == col0 + 3) v.w = 0.0f;
    *(float4*)(Wz + f) = v;
}

template<bool ZDIAG>
__global__ __launch_bounds__(256, 1) void li_gemm_gate(
    const float* __restrict__ A,    // [M, 512]
    const float* __restrict__ Wm,   // zero-diag W (ZDIAG=0) or raw W (ZDIAG=1)
    const float* __restrict__ bias, // [512]
    float* __restrict__ out,        // [M, 512]
    int M)
{
    __shared__ __align__(16) float As[2][BM][BK]; // [m][k], 64 B rows, swizzled k-groups
    __shared__ __align__(16) float Bs[2][BK][BN]; // [k][n], 1 KiB rows, linear

    const int tid  = threadIdx.x;
    const int lane = tid & 63;
    const int wv   = tid >> 6;   // wave 0..3
    const int tc   = tid & 15;   // column group (n)
    const int tr   = tid >> 4;   // row group (m)
    const int m0   = blockIdx.x * BM;
    const int n0   = blockIdx.y * BN;

    // --- A staging sources (per-lane, swizzled) ---
    // wave-instr j in {0,1}: dest rows wv*32 + j*16 + (lane>>2), dest k-group lane&3.
    // LDS[m][q] holds A[m][ q ^ s(m) ], s(m) = (m>>3)&3  -> conflict-free b128 reads.
    const int am0 = wv * 32 + (lane >> 2);
    const int am1 = am0 + 16;
    const int q0  = ((lane & 3) ^ ((am0 >> 3) & 3)) << 2;
    const int q1  = ((lane & 3) ^ ((am1 >> 3) & 3)) << 2;
    const float* aSrc0 = A + (size_t)(m0 + am0) * NUMD + q0;
    const float* aSrc1 = A + (size_t)(m0 + am1) * NUMD + q1;
    // --- B staging source: wave-instr r in {0..3} covers row wv*4+r (1 KiB each)
    const float* wSrc = Wm + (size_t)(wv * 4) * NUMD + n0 + lane * 4;

    float acc[TM][TN];
#pragma unroll
    for (int i = 0; i < TM; ++i)
#pragma unroll
        for (int j = 0; j < TN; ++j) acc[i][j] = 0.0f;

    // issue tile 0 into buffer 0
    GLOAD_LDS16(aSrc0, &As[0][wv * 32][0]);
    GLOAD_LDS16(aSrc1, &As[0][wv * 32 + 16][0]);
#pragma unroll
    for (int r = 0; r < 4; ++r)
        GLOAD_LDS16(wSrc + (size_t)r * NUMD, &Bs[0][wv * 4 + r][0]);
    aSrc0 += BK; aSrc1 += BK; wSrc += (size_t)BK * NUMD;

    for (int kt = 0; kt < NT; ++kt) {
        const int cur = kt & 1;
        // publish tile kt: each wave's own loads drained (vmcnt(0)) + barrier.
        // kt's loads were issued ~one full compute phase ago -> latency hidden.
        __syncthreads();

        // issue tile kt+1 into the other buffer (its last readers finished
        // before the barrier above)
        if (kt + 1 < NT) {
            const int nb = cur ^ 1;
            GLOAD_LDS16(aSrc0, &As[nb][wv * 32][0]);
            GLOAD_LDS16(aSrc1, &As[nb][wv * 32 + 16][0]);
#pragma unroll
            for (int r = 0; r < 4; ++r)
                GLOAD_LDS16(wSrc + (size_t)r * NUMD, &Bs[nb][wv * 4 + r][0]);
            aSrc0 += BK; aSrc1 += BK; wSrc += (size_t)BK * NUMD;
        }

        if (ZDIAG) {
            // zero diagonal elements of this W tile in LDS (exact w1 semantics)
            const int kk = kt * BK;
            if (tid < BK) {
                const int col = kk + tid - n0;
                if (col >= 0 && col < BN) Bs[cur][tid][col] = 0.0f;
            }
            __syncthreads();
        }

        // compute tile kt from buffer cur
#pragma unroll
        for (int g = 0; g < 4; ++g) {           // k-group of 4
            float4 af[TM];
#pragma unroll
            for (int i = 0; i < TM; ++i) {
                const int m = tr * TM + i;
                af[i] = *(const float4*)&As[cur][m][(g ^ ((m >> 3) & 3)) << 2];
            }
#pragma unroll
            for (int dk = 0; dk < 4; ++dk) {
                float b[TN];
#pragma unroll
                for (int c = 0; c < 4; ++c) {
                    float4 b4 = *(const float4*)&Bs[cur][g * 4 + dk][tc * 4 + 64 * c];
                    b[4 * c + 0] = b4.x; b[4 * c + 1] = b4.y;
                    b[4 * c + 2] = b4.z; b[4 * c + 3] = b4.w;
                }
#pragma unroll
                for (int i = 0; i < TM; ++i) {
                    const float a = ((const float*)&af[i])[dk];
#pragma unroll
                    for (int j = 0; j < TN; ++j)
                        acc[i][j] = fmaf(a, b[j], acc[i][j]);
                }
            }
        }
    }

    // epilogue: out[m][n] = in[m][n] * ((acc + b[n]) > 0)
    float bv[TN];
#pragma unroll
    for (int c = 0; c < 4; ++c) {
        float4 b4 = *(const float4*)(bias + n0 + tc * 4 + 64 * c);
        bv[4 * c + 0] = b4.x; bv[4 * c + 1] = b4.y;
        bv[4 * c + 2] = b4.z; bv[4 * c + 3] = b4.w;
    }

#pragma unroll
    for (int i = 0; i < TM; ++i) {
        const int gm = m0 + tr * TM + i;
        const float* inrow = A + (size_t)gm * NUMD + n0 + tc * 4;
        float* orow       = out + (size_t)gm * NUMD + n0 + tc * 4;
#pragma unroll
        for (int c = 0; c < 4; ++c) {
            float4 x = *(const float4*)(inrow + 64 * c);
            float4 o;
            o.x = (acc[i][4*c+0] + bv[4*c+0] > 0.0f) ? x.x : 0.0f;
            o.y = (acc[i][4*c+1] + bv[4*c+1] > 0.0f) ? x.y : 0.0f;
            o.z = (acc[i][4*c+2] + bv[4*c+2] > 0.0f) ? x.z : 0.0f;
            o.w = (acc[i][4*c+3] + bv[4*c+3] > 0.0f) ? x.w : 0.0f;
            *(float4*)(orow + 64 * c) = o;
        }
    }
}

extern "C" void kernel_launch(void* const* d_in, const int* in_sizes, int n_in,
                              void* d_out, int out_size, void* d_ws, size_t ws_size,
                              hipStream_t stream) {
    const float* A    = (const float*)d_in[0]; // inputs [8*4096, 512]
    const float* W    = (const float*)d_in[1]; // w [512, 512]
    const float* bias = (const float*)d_in[2]; // b [512]
    float* out        = (float*)d_out;

    const int M = in_sizes[0] / NUMD; // 32768
    dim3 grid(M / BM, NUMD / BN);     // (256, 2)

    const size_t wbytes = (size_t)NUMD * NUMD * sizeof(float);
    if (ws_size >= wbytes) {
        float* Wz = (float*)d_ws;
        zero_diag_kernel<<<dim3(NUMD * NUMD / (4 * 256)), 256, 0, stream>>>(W, Wz);
        li_gemm_gate<false><<<grid, 256, 0, stream>>>(A, Wz, bias, out, M);
    } else {
        li_gemm_gate<true><<<grid, 256, 0, stream>>>(A, W, bias, out, M);
    }
}

// Round 5
// 282.435 us; speedup vs baseline: 1.6719x; 1.0027x over previous
//
#include <hip/hip_runtime.h>
#include <stdint.h>

// LateralInhibition: out = inputs * ((inputs @ w1 + b) > 0), w1 = w with zero diag.
// inputs: [M=32768, 512] fp32 row-major; w: [512,512] fp32 row-major (w[k][n]).
// fp32 vector-ALU SGEMM (no fp32 MFMA on CDNA4).
//
// v5 = v4 + v_pk_fma_f32 (packed 2xfp32 FMA, VOP3P) inner loop.
//  - v4 post-mortem: 205us, VALUBusy 67%, conflicts 0. VALU floor 109us (53%
//    duty), LDS floor ~123us (60% duty) -> stall-bound, both pipes ~balanced
//    (256 vs 288 cyc/wave/k-step) so every bubble hits the critical path.
//  - pk_fma halves FMA issue slots (64 pk vs 128 scalar per thread per k).
//    A-broadcast via op_sel (lo/lo or hi/hi of the af pair) = zero extra movs.
//  - A/B experiment: if CDNA4 keeps MI250X-style double-rate packed fp32,
//    dur -> ~150us; if half-rate, exactly neutral.
// Structure (unchanged from v4): BM=128 BN=256 BK=16, 8x16/thread, 256 thr,
//  global_load_lds width=16 both operands, 2-phase double-buffer, A stored
//  [m][k] with XOR swizzle q^=(m>>3)&3 on both global source and LDS read,
//  Bs linear [16][256], diag pre-zeroed into d_ws (exact LDS fallback).

#define NUMD 512
#define BM 128
#define BN 256
#define BK 16
#define TM 8
#define TN 16
#define NT (NUMD / BK)   // 32

typedef float f32x2 __attribute__((ext_vector_type(2)));

#define GLOAD_LDS16(g, l)                                                      \
  __builtin_amdgcn_global_load_lds(                                            \
      (const __attribute__((address_space(1))) void*)(g),                      \
      (__attribute__((address_space(3))) void*)(l), 16, 0, 0)

__global__ __launch_bounds__(256) void zero_diag_kernel(
    const float* __restrict__ W, float* __restrict__ Wz)
{
    const int f = (int)(blockIdx.x * blockDim.x + threadIdx.x) * 4;
    const int row  = f >> 9;
    const int col0 = f & 511;
    float4 v = *(const float4*)(W + f);
    if (row == col0 + 0) v.x = 0.0f;
    if (row == col0 + 1) v.y = 0.0f;
    if (row == col0 + 2) v.z = 0.0f;
    if (row == col0 + 3) v.w = 0.0f;
    *(float4*)(Wz + f) = v;
}

template<bool ZDIAG>
__global__ __launch_bounds__(256, 1) void li_gemm_gate(
    const float* __restrict__ A,    // [M, 512]
    const float* __restrict__ Wm,   // zero-diag W (ZDIAG=0) or raw W (ZDIAG=1)
    const float* __restrict__ bias, // [512]
    float* __restrict__ out,        // [M, 512]
    int M)
{
    __shared__ __align__(16) float As[2][BM][BK]; // [m][k], swizzled k-groups
    __shared__ __align__(16) float Bs[2][BK][BN]; // [k][n], linear

    const int tid  = threadIdx.x;
    const int lane = tid & 63;
    const int wv   = tid >> 6;   // wave 0..3
    const int tc   = tid & 15;   // column group (n)
    const int tr   = tid >> 4;   // row group (m)
    const int m0   = blockIdx.x * BM;
    const int n0   = blockIdx.y * BN;

    // --- A staging sources (per-lane, swizzled; see v4 comment) ---
    const int am0 = wv * 32 + (lane >> 2);
    const int am1 = am0 + 16;
    const int q0  = ((lane & 3) ^ ((am0 >> 3) & 3)) << 2;
    const int q1  = ((lane & 3) ^ ((am1 >> 3) & 3)) << 2;
    const float* aSrc0 = A + (size_t)(m0 + am0) * NUMD + q0;
    const float* aSrc1 = A + (size_t)(m0 + am1) * NUMD + q1;
    // --- B staging source: wave-instr r in {0..3} covers row wv*4+r
    const float* wSrc = Wm + (size_t)(wv * 4) * NUMD + n0 + lane * 4;

    f32x2 acc2[TM][TN / 2];
#pragma unroll
    for (int i = 0; i < TM; ++i)
#pragma unroll
        for (int j2 = 0; j2 < TN / 2; ++j2) acc2[i][j2] = f32x2{0.0f, 0.0f};

    // issue tile 0 into buffer 0
    GLOAD_LDS16(aSrc0, &As[0][wv * 32][0]);
    GLOAD_LDS16(aSrc1, &As[0][wv * 32 + 16][0]);
#pragma unroll
    for (int r = 0; r < 4; ++r)
        GLOAD_LDS16(wSrc + (size_t)r * NUMD, &Bs[0][wv * 4 + r][0]);
    aSrc0 += BK; aSrc1 += BK; wSrc += (size_t)BK * NUMD;

    for (int kt = 0; kt < NT; ++kt) {
        const int cur = kt & 1;
        // publish tile kt (vmcnt(0)+barrier); kt's loads were issued one full
        // compute phase (~4000 cyc) ago -> latency hidden.
        __syncthreads();

        // issue tile kt+1 into the other buffer
        if (kt + 1 < NT) {
            const int nb = cur ^ 1;
            GLOAD_LDS16(aSrc0, &As[nb][wv * 32][0]);
            GLOAD_LDS16(aSrc1, &As[nb][wv * 32 + 16][0]);
#pragma unroll
            for (int r = 0; r < 4; ++r)
                GLOAD_LDS16(wSrc + (size_t)r * NUMD, &Bs[nb][wv * 4 + r][0]);
            aSrc0 += BK; aSrc1 += BK; wSrc += (size_t)BK * NUMD;
        }

        if (ZDIAG) {
            const int kk = kt * BK;
            if (tid < BK) {
                const int col = kk + tid - n0;
                if (col >= 0 && col < BN) Bs[cur][tid][col] = 0.0f;
            }
            __syncthreads();
        }

        // compute tile kt from buffer cur
#pragma unroll
        for (int g = 0; g < 4; ++g) {           // k-group of 4
            float4 af[TM];
#pragma unroll
            for (int i = 0; i < TM; ++i) {
                const int m = tr * TM + i;
                af[i] = *(const float4*)&As[cur][m][(g ^ ((m >> 3) & 3)) << 2];
            }
#pragma unroll
            for (int dk = 0; dk < 4; ++dk) {
                f32x2 b2[TN / 2];
#pragma unroll
                for (int c = 0; c < 4; ++c) {
                    float4 b4 = *(const float4*)&Bs[cur][g * 4 + dk][tc * 4 + 64 * c];
                    b2[2 * c + 0] = f32x2{b4.x, b4.y};
                    b2[2 * c + 1] = f32x2{b4.z, b4.w};
                }
#pragma unroll
                for (int i = 0; i < TM; ++i) {
                    // af[i] = 2 even-aligned f32 pairs; dk>>1 picks the pair,
                    // dk&1 picks the half broadcast via op_sel (no movs).
                    f32x2 ap = ((const f32x2*)&af[i])[dk >> 1];
#pragma unroll
                    for (int j2 = 0; j2 < TN / 2; ++j2) {
                        if ((dk & 1) == 0)
                            asm("v_pk_fma_f32 %0, %1, %2, %0 op_sel:[0,0,0] op_sel_hi:[0,1,1]"
                                : "+v"(acc2[i][j2]) : "v"(ap), "v"(b2[j2]));
                        else
                            asm("v_pk_fma_f32 %0, %1, %2, %0 op_sel:[1,0,0] op_sel_hi:[1,1,1]"
                                : "+v"(acc2[i][j2]) : "v"(ap), "v"(b2[j2]));
                    }
                }
            }
        }
    }

    // epilogue: out[m][n] = in[m][n] * ((acc + b[n]) > 0)
    float bv[TN];
#pragma unroll
    for (int c = 0; c < 4; ++c) {
        float4 b4 = *(const float4*)(bias + n0 + tc * 4 + 64 * c);
        bv[4 * c + 0] = b4.x; bv[4 * c + 1] = b4.y;
        bv[4 * c + 2] = b4.z; bv[4 * c + 3] = b4.w;
    }

#pragma unroll
    for (int i = 0; i < TM; ++i) {
        const int gm = m0 + tr * TM + i;
        const float* inrow = A + (size_t)gm * NUMD + n0 + tc * 4;
        float* orow       = out + (size_t)gm * NUMD + n0 + tc * 4;
#pragma unroll
        for (int c = 0; c < 4; ++c) {
            float4 x = *(const float4*)(inrow + 64 * c);
            const f32x2 lo = acc2[i][2 * c + 0];
            const f32x2 hi = acc2[i][2 * c + 1];
            float4 o;
            o.x = (lo.x + bv[4*c+0] > 0.0f) ? x.x : 0.0f;
            o.y = (lo.y + bv[4*c+1] > 0.0f) ? x.y : 0.0f;
            o.z = (hi.x + bv[4*c+2] > 0.0f) ? x.z : 0.0f;
            o.w = (hi.y + bv[4*c+3] > 0.0f) ? x.w : 0.0f;
            *(float4*)(orow + 64 * c) = o;
        }
    }
}

extern "C" void kernel_launch(void* const* d_in, const int* in_sizes, int n_in,
                              void* d_out, int out_size, void* d_ws, size_t ws_size,
                              hipStream_t stream) {
    const float* A    = (const float*)d_in[0]; // inputs [8*4096, 512]
    const float* W    = (const float*)d_in[1]; // w [512, 512]
    const float* bias = (const float*)d_in[2]; // b [512]
    float* out        = (float*)d_out;

    const int M = in_sizes[0] / NUMD; // 32768
    dim3 grid(M / BM, NUMD / BN);     // (256, 2)

    const size_t wbytes = (size_t)NUMD * NUMD * sizeof(float);
    if (ws_size >= wbytes) {
        float* Wz = (float*)d_ws;
        zero_diag_kernel<<<dim3(NUMD * NUMD / (4 * 256)), 256, 0, stream>>>(W, Wz);
        li_gemm_gate<false><<<grid, 256, 0, stream>>>(A, Wz, bias, out, M);
    } else {
        li_gemm_gate<true><<<grid, 256, 0, stream>>>(A, W, bias, out, M);
    }
}